// Round 3
// baseline (1238.685 us; speedup 1.0000x reference)
//
#include <hip/hip_runtime.h>
#include <math.h>

#define HW 65536           // 256*256

// ---------------------------------------------------------------------------
// Bias MLP: biasT[n][j][i] = ( relu(rel[i,j,:] @ w1^T + b1) @ w2^T + b2 )[n]
// ---------------------------------------------------------------------------
__global__ __launch_bounds__(256) void bias_mlp_kernel(
    const float* __restrict__ w1, const float* __restrict__ b1,
    const float* __restrict__ w2, const float* __restrict__ b2,
    float* __restrict__ biasT)
{
    int id = blockIdx.x * 256 + threadIdx.x;   // 4096 = 64*64
    int i = id >> 6, j = id & 63;
    float dy = (float)((i >> 3) - (j >> 3));
    float dx = (float)((i & 7) - (j & 7));
    float r0 = copysignf(log1pf(fabsf(dy)), dy);
    float r1 = copysignf(log1pf(fabsf(dx)), dx);
    float a0 = b2[0], a1 = b2[1], a2 = b2[2];
    for (int m = 0; m < 256; ++m) {
        float h = fmaf(r0, w1[2*m], fmaf(r1, w1[2*m+1], b1[m]));
        h = fmaxf(h, 0.f);
        a0 = fmaf(h, w2[m],       a0);
        a1 = fmaf(h, w2[256 + m], a1);
        a2 = fmaf(h, w2[512 + m], a2);
    }
    biasT[(0*64 + j)*64 + i] = a0;
    biasT[(1*64 + j)*64 + i] = a1;
    biasT[(2*64 + j)*64 + i] = a2;
}

// ---------------------------------------------------------------------------
// 1x1-conv GEMM: out[b][o][pos] = (sum_c W[o][c] * X[b][c][pos] + bias)*scale
// Batch-relative: X/out pointers are pre-offset by the caller's chunk base.
// Tile: M=96, N=128 positions, K chunks of 32; per-thread 12x4 micro-tile.
// grid.y: 0 -> W0/bias0/out0 ; 1 -> W12 rows 0..95 (K, scaled) ; 2 -> rows 96..191 (V)
// ---------------------------------------------------------------------------
__global__ __launch_bounds__(256) void gemm1x1_kernel(
    const float* __restrict__ X,
    const float* __restrict__ W0,  const float* __restrict__ W12,
    const float* __restrict__ bias0, const float* __restrict__ bias12,
    const float* __restrict__ lsptr,
    float* __restrict__ out0, float* __restrict__ out1, float* __restrict__ out2)
{
    const int tid = threadIdx.x;
    const int z = blockIdx.y;
    // XCD-aware bijective swizzle (gridDim.x multiple of 8)
    int t = (blockIdx.x & 7) * (gridDim.x >> 3) + (blockIdx.x >> 3);
    const int b    = t >> 9;          // 512 tiles per batch image
    const int pos0 = (t & 511) << 7;  // 128 positions per tile

    const float* Wmat = (z == 0) ? W0     : (z == 1 ? W12    : W12 + 96*96);
    const float* bias = (z == 0) ? bias0  : (z == 1 ? bias12 : bias12 + 96);
    float*       out  = (z == 0) ? out0   : (z == 1 ? out1   : out2);
    float scale = 1.0f;
    if (z == 1)  // fold k * HD^-0.5 * exp(min(ls, log 100)) into stored K
        scale = __expf(fminf(lsptr[0], 4.6051702f)) * 0.17677669529663687f;

    __shared__ float Xs[32][128];
    __shared__ float Ws[32][96];

    const int tx = tid & 31, ty = tid >> 5;   // 32 pos-groups x 8 o-groups
    float acc[12][4];
    #pragma unroll
    for (int u = 0; u < 12; ++u)
        #pragma unroll
        for (int p = 0; p < 4; ++p) acc[u][p] = 0.f;

    const float* Xb = X + (size_t)b * 96 * HW + pos0;

    for (int kc = 0; kc < 96; kc += 32) {
        #pragma unroll
        for (int jj = 0; jj < 4; ++jj) {            // X chunk: 1024 float4
            int i4 = tid + jj*256;
            int kr = i4 >> 5, p4 = i4 & 31;
            float4 v = *reinterpret_cast<const float4*>(Xb + (size_t)(kc + kr)*HW + p4*4);
            *reinterpret_cast<float4*>(&Xs[kr][p4*4]) = v;
        }
        #pragma unroll
        for (int jj = 0; jj < 3; ++jj) {            // W chunk: transpose into [k][o]
            int i4 = tid + jj*256;
            int o = i4 >> 3, c4 = i4 & 7;
            float4 v = *reinterpret_cast<const float4*>(Wmat + o*96 + kc + c4*4);
            Ws[c4*4+0][o] = v.x; Ws[c4*4+1][o] = v.y;
            Ws[c4*4+2][o] = v.z; Ws[c4*4+3][o] = v.w;
        }
        __syncthreads();
        #pragma unroll 8
        for (int k = 0; k < 32; ++k) {
            float4 xr = *reinterpret_cast<const float4*>(&Xs[k][tx*4]);
            float4 wa = *reinterpret_cast<const float4*>(&Ws[k][ty*12]);
            float4 wb = *reinterpret_cast<const float4*>(&Ws[k][ty*12+4]);
            float4 wc = *reinterpret_cast<const float4*>(&Ws[k][ty*12+8]);
            float wv[12] = {wa.x,wa.y,wa.z,wa.w, wb.x,wb.y,wb.z,wb.w, wc.x,wc.y,wc.z,wc.w};
            float xv[4]  = {xr.x, xr.y, xr.z, xr.w};
            #pragma unroll
            for (int u = 0; u < 12; ++u)
                #pragma unroll
                for (int p = 0; p < 4; ++p)
                    acc[u][p] = fmaf(wv[u], xv[p], acc[u][p]);
        }
        __syncthreads();
    }

    float* ob = out + (size_t)b * 96 * HW + pos0 + tx*4;
    #pragma unroll
    for (int u = 0; u < 12; ++u) {
        int o = ty*12 + u;
        float bv = bias[o];
        float4 r;
        r.x = (acc[u][0] + bv) * scale;
        r.y = (acc[u][1] + bv) * scale;
        r.z = (acc[u][2] + bv) * scale;
        r.w = (acc[u][3] + bv) * scale;
        *reinterpret_cast<float4*>(ob + (size_t)o * HW) = r;
    }
}

// ---------------------------------------------------------------------------
// Depthwise 5x5, reflect-pad 2.  One block = one (b,c) and 8 image rows.
// ---------------------------------------------------------------------------
__global__ __launch_bounds__(256) void dwconv5x5_kernel(
    const float* __restrict__ Q, const float* __restrict__ dw,
    const float* __restrict__ db, float* __restrict__ out)
{
    int bid = (blockIdx.x & 7) * (gridDim.x >> 3) + (blockIdx.x >> 3);
    const int bc = bid >> 5;           // b_rel*96 + c
    const int h0 = (bid & 31) << 3;
    const int c  = bc % 96;
    const int tid = threadIdx.x;

    __shared__ float t[12][264];       // rows h0-2..h0+9, img col w at LDS col w+4

    const float* Qb = Q + (size_t)bc * HW;
    #pragma unroll
    for (int jj = 0; jj < 3; ++jj) {   // 768 float4 = 12 rows x 64
        int i4 = tid + jj*256;
        int r = i4 >> 6, c4 = i4 & 63;
        int imr = h0 - 2 + r;
        imr = imr < 0 ? -imr : (imr > 255 ? 510 - imr : imr);
        float4 v = *reinterpret_cast<const float4*>(Qb + imr*256 + c4*4);
        *reinterpret_cast<float4*>(&t[r][4 + c4*4]) = v;
    }
    if (tid < 48) {                    // horizontal reflect halo: 12 rows x 4 cols
        int r = tid >> 2, which = tid & 3;
        int imr = h0 - 2 + r;
        imr = imr < 0 ? -imr : (imr > 255 ? 510 - imr : imr);
        int L  = (which < 2) ? (2 + which) : (258 + which);     // 2,3,260,261
        int gc = (which == 0) ? 2 : (which == 1) ? 1 : (which == 2) ? 254 : 253;
        t[r][L] = Qb[imr*256 + gc];
    }
    __syncthreads();

    float w[25];
    #pragma unroll
    for (int q = 0; q < 25; ++q) w[q] = dw[c*25 + q];
    const float bv = db[c];

    float* ob = out + (size_t)bc * HW + h0*256;
    #pragma unroll
    for (int jj = 0; jj < 8; ++jj) {
        int px = tid + jj*256;
        int r = px >> 8, wcol = px & 255;
        float acc = bv;
        #pragma unroll
        for (int ky = 0; ky < 5; ++ky)
            #pragma unroll
            for (int kx = 0; kx < 5; ++kx)
                acc = fmaf(w[ky*5+kx], t[r+ky][wcol + kx + 2], acc);
        ob[px] = acc;
    }
}

// ---------------------------------------------------------------------------
// Window attention: block = one 8x8 window (192 thr), wave = head, lane = query pos.
// K already folded with HD^-0.5 * exp(min(ls,log100)).  Layouts all [b][c][h][w].
// ---------------------------------------------------------------------------
__global__ __launch_bounds__(192) void winattn_kernel(
    const float* __restrict__ q, const float* __restrict__ K,
    const float* __restrict__ V, const float* __restrict__ biasT,
    float* __restrict__ out)
{
    int t = (blockIdx.x & 7) * (gridDim.x >> 3) + (blockIdx.x >> 3);
    const int b = t >> 10, wy = (t >> 5) & 31, wx = t & 31;
    const int tid  = threadIdx.x;
    const int head = tid >> 6, lane = tid & 63;

    __shared__ float Kl[64][100];   // [pos][chan], pad 100: b128-aligned reads
    __shared__ float Vl[64][100];

    const size_t wbase = ((size_t)b * 96 * 256 + (size_t)wy * 8) * 256 + wx * 8;

    for (int i = tid; i < 6144; i += 192) {
        int cc = i >> 6, p = i & 63;
        size_t g = wbase + (size_t)cc * HW + (size_t)(p >> 3) * 256 + (p & 7);
        Kl[p][cc] = K[g];
        Vl[p][cc] = V[g];
    }

    const int py = lane >> 3, px = lane & 7;
    const size_t qbase = wbase + (size_t)head * 32 * HW + py * 256 + px;
    float qr[32];
    #pragma unroll
    for (int d = 0; d < 32; ++d) qr[d] = q[qbase + (size_t)d * HW];

    __syncthreads();

    float s[64];
    const float* bT = biasT + head * 4096 + lane;   // biasT[head][j][lane]
    #pragma unroll
    for (int j = 0; j < 64; ++j) {
        const float4* kr = reinterpret_cast<const float4*>(&Kl[j][head*32]);
        float dot = 0.f;
        #pragma unroll
        for (int d4 = 0; d4 < 8; ++d4) {
            float4 kv = kr[d4];
            dot = fmaf(qr[d4*4+0], kv.x, dot);
            dot = fmaf(qr[d4*4+1], kv.y, dot);
            dot = fmaf(qr[d4*4+2], kv.z, dot);
            dot = fmaf(qr[d4*4+3], kv.w, dot);
        }
        s[j] = dot + bT[j*64];
    }
    float m = s[0];
    #pragma unroll
    for (int j = 1; j < 64; ++j) m = fmaxf(m, s[j]);
    float sum = 0.f;
    #pragma unroll
    for (int j = 0; j < 64; ++j) { s[j] = __expf(s[j] - m); sum += s[j]; }
    const float inv = 1.0f / sum;

    float acc[32];
    #pragma unroll
    for (int d = 0; d < 32; ++d) acc[d] = 0.f;
    #pragma unroll
    for (int j = 0; j < 64; ++j) {
        float pj = s[j];
        const float4* vr = reinterpret_cast<const float4*>(&Vl[j][head*32]);
        #pragma unroll
        for (int d4 = 0; d4 < 8; ++d4) {
            float4 vv = vr[d4];
            acc[d4*4+0] = fmaf(pj, vv.x, acc[d4*4+0]);
            acc[d4*4+1] = fmaf(pj, vv.y, acc[d4*4+1]);
            acc[d4*4+2] = fmaf(pj, vv.z, acc[d4*4+2]);
            acc[d4*4+3] = fmaf(pj, vv.w, acc[d4*4+3]);
        }
    }
    #pragma unroll
    for (int d = 0; d < 32; ++d)
        out[qbase + (size_t)d * HW] = acc[d] * inv;
}

// ---------------------------------------------------------------------------
extern "C" void kernel_launch(void* const* d_in, const int* in_sizes, int n_in,
                              void* d_out, int out_size, void* d_ws, size_t ws_size,
                              hipStream_t stream)
{
    const float* X     = (const float*)d_in[0];
    const float* Wq    = (const float*)d_in[1];
    const float* bq    = (const float*)d_in[2];
    const float* Wkv   = (const float*)d_in[3];
    const float* bkv   = (const float*)d_in[4];
    const float* dww   = (const float*)d_in[5];
    const float* dwb   = (const float*)d_in[6];
    const float* Wproj = (const float*)d_in[7];
    const float* bproj = (const float*)d_in[8];
    const float* ls    = (const float*)d_in[9];
    const float* mw1   = (const float*)d_in[10];
    const float* mb1   = (const float*)d_in[11];
    const float* mw2   = (const float*)d_in[12];
    const float* mb2   = (const float*)d_in[13];
    float* out = (float*)d_out;

    // Scratch: bias table + 3 per-chunk tensors (Q, K, V).  convQ lives in
    // d_out (same layout; dead before proj GEMM overwrites it).
    // Pick largest batch-chunk nb ∈ {8,4,2,1} that fits ws_size.
    const size_t perBatch = (size_t)96 * HW;          // elements per image
    int nb = 8;
    while (nb > 1 &&
           (12288 + (size_t)3 * nb * perBatch) * sizeof(float) > ws_size)
        nb >>= 1;

    float* biasT = (float*)d_ws;                      // [3][64][64]
    float* f0 = biasT + 12288;                        // Q / attn-out
    float* f1 = f0 + (size_t)nb * perBatch;           // K (pre-scaled)
    float* f2 = f1 + (size_t)nb * perBatch;           // V

    bias_mlp_kernel<<<16, 256, 0, stream>>>(mw1, mb1, mw2, mb2, biasT);

    for (int b0 = 0; b0 < 8; b0 += nb) {
        const float* Xc  = X   + (size_t)b0 * perBatch;
        float*       oc  = out + (size_t)b0 * perBatch;  // also convQ scratch
        gemm1x1_kernel<<<dim3(512 * nb, 3), 256, 0, stream>>>(
            Xc, Wq, Wkv, bq, bkv, ls, f0, f1, f2);
        dwconv5x5_kernel<<<3072 * nb, 256, 0, stream>>>(f0, dww, dwb, oc);
        winattn_kernel<<<1024 * nb, 192, 0, stream>>>(oc, f1, f2, biasT, f0);
        gemm1x1_kernel<<<dim3(512 * nb, 1), 256, 0, stream>>>(
            f0, Wproj, Wkv, bproj, bkv, ls, oc, f1, f2);
    }
}